// Round 1
// 283.096 us; speedup vs baseline: 1.0305x; 1.0305x over previous
//
#include <hip/hip_runtime.h>
#include <hip/hip_bf16.h>

#define NN 50000
#define EE 800000
#define ET (NN + EE)   // edges incl. self-loops = 850000
#define SG ((NN + 255) / 256)   // scan blocks = 196
#define GB1 ((NN + 63) / 64)    // gemm1 blocks = 782

typedef __attribute__((ext_vector_type(8))) short short8;
typedef __attribute__((ext_vector_type(4))) float f32x4;

__device__ __forceinline__ float bf2f(unsigned short u) {
    union { unsigned int i; float f; } v; v.i = ((unsigned int)u) << 16; return v.f;
}
__device__ __forceinline__ unsigned short f2bf(float f) {
    __hip_bfloat16 h = __float2bfloat16(f);
    return *reinterpret_cast<unsigned short*>(&h);
}
// lrelu(x) = max(x, 0.2x): valid for all x since 0.2x > x iff x < 0. 2 VALU ops.
__device__ __forceinline__ float lrelu(float e) { return fmaxf(e, 0.2f * e); }

// ---------------- CSR build ----------------
// cnt starts 0 (memset); self-loop handled as "+i" in scan3 arithmetic.

__global__ void k_hist(const int* __restrict__ dst, int* __restrict__ cnt) {
    int i = blockIdx.x * blockDim.x + threadIdx.x;
    if (i < EE) atomicAdd(&cnt[dst[i]], 1);
}

__global__ __launch_bounds__(256) void k_scan1(const int* __restrict__ cnt,
                                               int* __restrict__ tmp, int* __restrict__ bsum) {
    int b = blockIdx.x, t = threadIdx.x, i = b * 256 + t;
    int lane = t & 63, w = t >> 6;
    int v = (i < NN) ? cnt[i] : 0;
    int s = v;
    #pragma unroll
    for (int off = 1; off < 64; off <<= 1) {
        int u = __shfl_up(s, off);
        if (lane >= off) s += u;
    }
    __shared__ int ws[4];
    if (lane == 63) ws[w] = s;
    __syncthreads();
    if (t == 0) {
        int a = 0;
        #pragma unroll
        for (int k = 0; k < 4; k++) { int x = ws[k]; ws[k] = a; a += x; }
        bsum[b] = a;
    }
    __syncthreads();
    s += ws[w];
    if (i < NN) tmp[i] = s;   // inclusive within block (edge counts only)
}

__global__ __launch_bounds__(256) void k_scan2(const int* __restrict__ bsum, int* __restrict__ boff) {
    int t = threadIdx.x, lane = t & 63, w = t >> 6;
    int v = (t < SG) ? bsum[t] : 0;
    int s = v;
    #pragma unroll
    for (int off = 1; off < 64; off <<= 1) {
        int u = __shfl_up(s, off);
        if (lane >= off) s += u;
    }
    __shared__ int ws[4];
    if (lane == 63) ws[w] = s;
    __syncthreads();
    if (t == 0) {
        int a = 0;
        #pragma unroll
        for (int k = 0; k < 4; k++) { int x = ws[k]; ws[k] = a; a += x; }
    }
    __syncthreads();
    s += ws[w];
    if (t < SG) boff[t] = s - v;   // exclusive
}

// rowptr[i+1] = scan(cnt)[i] + (i+1)  (the +i+1 accounts for one self-loop per node)
__global__ void k_scan3_prep(const int* __restrict__ tmp, const int* __restrict__ boff,
                             int* __restrict__ rowptr, int* __restrict__ writeptr,
                             int* __restrict__ csr) {
    int i = blockIdx.x * blockDim.x + threadIdx.x;
    if (i == 0) rowptr[0] = 0;
    if (i < NN) {
        int base = boff[i >> 8];
        int incl = tmp[i] + base + i + 1;
        rowptr[i + 1] = incl;
        int excl = ((i & 255) ? tmp[i - 1] + base : base) + i;   // == rowptr[i]
        csr[excl] = i;            // self-loop first
        writeptr[i] = excl + 1;
    }
}

// ---------------- MFMA bf16 GEMM body (device fn, shared by fused + standalone) ----------------
template<int K, int N, int NH, bool A_BF16>
__device__ __forceinline__ void gemm_body(
    int bid, const void* __restrict__ Aptr, const float* __restrict__ W,
    const float* __restrict__ atts, const float* __restrict__ attd,
    unsigned short* __restrict__ C, float* __restrict__ as_, float* __restrict__ ad_,
    int M)
{
    constexpr int KU  = K / 8;        // 16B units per row
    constexpr int KUH = KU / 2;       // units per K-half
    constexpr int KC  = K / 32;       // mfma K-chunks
    constexpr int NW  = N / 4;        // cols per wave
    constexpr int NI  = NW / 16;      // 16-col tiles per wave
    constexpr int ABYTES = 64 * KU * 16;
    constexpr int BBYTES = N * KUH * 16;
    constexpr int SMEM = ABYTES + BBYTES + (NH == 1 ? 2048 : 0);
    __shared__ char smem[SMEM];
    char* Ash = smem;
    char* Bsh = smem + ABYTES;
    unsigned short* Csh = (unsigned short*)smem;          // overlay after compute
    float* scsh = (float*)(smem + ABYTES + BBYTES);       // NH==1 only

    int t = threadIdx.x;
    int lane = t & 63, w = t >> 6;
    int colL = lane & 15, quad = lane >> 4;
    int m0 = bid * 64;

    // ---- stage A (full K) ----
    {
        constexpr int CNT = 64 * KU / 256;
        #pragma unroll
        for (int i = 0; i < CNT; i++) {
            int v = t + 256 * i;
            int m = v / KU, u = v % KU;
            int gr = m0 + m; if (gr >= M) gr = M - 1;
            short8 val;
            if (A_BF16) {
                val = *(const short8*)((const unsigned short*)Aptr + (size_t)gr * K + u * 8);
            } else {
                const float* Af = (const float*)Aptr;
                float4 lo = *(const float4*)(Af + (size_t)gr * K + u * 8);
                float4 hi = *(const float4*)(Af + (size_t)gr * K + u * 8 + 4);
                val[0] = (short)f2bf(lo.x); val[1] = (short)f2bf(lo.y);
                val[2] = (short)f2bf(lo.z); val[3] = (short)f2bf(lo.w);
                val[4] = (short)f2bf(hi.x); val[5] = (short)f2bf(hi.y);
                val[6] = (short)f2bf(hi.z); val[7] = (short)f2bf(hi.w);
            }
            *(short8*)(Ash + ((size_t)m * KU + (u ^ (m & 7))) * 16) = val;
        }
    }

    f32x4 acc[4][NI];
    #pragma unroll
    for (int mi = 0; mi < 4; mi++)
        #pragma unroll
        for (int ni = 0; ni < NI; ni++) acc[mi][ni] = (f32x4){0.f, 0.f, 0.f, 0.f};

    #pragma unroll
    for (int kh = 0; kh < 2; kh++) {
        __syncthreads();
        // ---- stage B half ----
        {
            constexpr int CNT = N * KUH / 256;
            #pragma unroll
            for (int i = 0; i < CNT; i++) {
                int v = t + 256 * i;
                int n = v / KUH, uu = v % KUH;
                int u = kh * KUH + uu;
                float4 lo = *(const float4*)(W + (size_t)n * K + u * 8);
                float4 hi = *(const float4*)(W + (size_t)n * K + u * 8 + 4);
                short8 val;
                val[0] = (short)f2bf(lo.x); val[1] = (short)f2bf(lo.y);
                val[2] = (short)f2bf(lo.z); val[3] = (short)f2bf(lo.w);
                val[4] = (short)f2bf(hi.x); val[5] = (short)f2bf(hi.y);
                val[6] = (short)f2bf(hi.z); val[7] = (short)f2bf(hi.w);
                *(short8*)(Bsh + ((size_t)n * KUH + (uu ^ (n & 7))) * 16) = val;
            }
        }
        __syncthreads();
        #pragma unroll
        for (int kcl = 0; kcl < KC / 2; kcl++) {
            int uA = (kh * (KC / 2) + kcl) * 4 + quad;
            int uB = kcl * 4 + quad;
            short8 bf[NI];
            #pragma unroll
            for (int ni = 0; ni < NI; ni++) {
                int n = w * NW + ni * 16 + colL;
                bf[ni] = *(const short8*)(Bsh + ((size_t)n * KUH + (uB ^ (n & 7))) * 16);
            }
            #pragma unroll
            for (int mi = 0; mi < 4; mi++) {
                int m = mi * 16 + colL;
                short8 af = *(const short8*)(Ash + ((size_t)m * KU + (uA ^ (m & 7))) * 16);
                #pragma unroll
                for (int ni = 0; ni < NI; ni++)
                    acc[mi][ni] = __builtin_amdgcn_mfma_f32_16x16x32_bf16(af, bf[ni], acc[mi][ni], 0, 0, 0);
            }
        }
    }
    __syncthreads();   // all LDS reads done; Csh/scsh overlay safe

    // ---- attention scores ----
    float asv[NI], adv[NI];
    #pragma unroll
    for (int ni = 0; ni < NI; ni++) {
        int na = (NH == 4) ? (w * 64 + ni * 16 + colL) : (w * 16 + colL);
        asv[ni] = atts[na];
        adv[ni] = attd[na];
    }
    #pragma unroll
    for (int mi = 0; mi < 4; mi++) {
        float ps[4] = {0.f, 0.f, 0.f, 0.f}, pd[4] = {0.f, 0.f, 0.f, 0.f};
        #pragma unroll
        for (int ni = 0; ni < NI; ni++)
            #pragma unroll
            for (int r = 0; r < 4; r++) {
                ps[r] += acc[mi][ni][r] * asv[ni];
                pd[r] += acc[mi][ni][r] * adv[ni];
            }
        #pragma unroll
        for (int off = 1; off < 16; off <<= 1)
            #pragma unroll
            for (int r = 0; r < 4; r++) {
                ps[r] += __shfl_xor(ps[r], off);
                pd[r] += __shfl_xor(pd[r], off);
            }
        if (colL == 0) {
            #pragma unroll
            for (int r = 0; r < 4; r++) {
                int rloc = mi * 16 + quad * 4 + r;
                if (NH == 4) {
                    int row = m0 + rloc;
                    if (row < M) {
                        as_[(size_t)row * 4 + w] = ps[r];
                        ad_[(size_t)row * 4 + w] = pd[r];
                    }
                } else {
                    scsh[(w * 64 + rloc) * 2 + 0] = ps[r];
                    scsh[(w * 64 + rloc) * 2 + 1] = pd[r];
                }
            }
        }
    }

    // ---- C repack to LDS (bf16) ----
    #pragma unroll
    for (int mi = 0; mi < 4; mi++)
        #pragma unroll
        for (int ni = 0; ni < NI; ni++)
            #pragma unroll
            for (int r = 0; r < 4; r++)
                Csh[(size_t)(mi * 16 + quad * 4 + r) * (N + 8) + w * NW + ni * 16 + colL] =
                    f2bf(acc[mi][ni][r]);
    __syncthreads();

    // ---- coalesced global store ----
    {
        constexpr int CNT = 64 * (N / 8) / 256;
        #pragma unroll
        for (int i = 0; i < CNT; i++) {
            int v = t + 256 * i;
            int m = v / (N / 8), u = v % (N / 8);
            int row = m0 + m;
            if (row < M)
                *(short8*)(C + (size_t)row * N + u * 8) =
                    *(const short8*)(Csh + (size_t)m * (N + 8) + u * 8);
        }
    }
    if (NH == 1 && t < 64) {
        int row = m0 + t;
        if (row < M) {
            float s = 0.f, d = 0.f;
            #pragma unroll
            for (int ww = 0; ww < 4; ww++) {
                s += scsh[(ww * 64 + t) * 2 + 0];
                d += scsh[(ww * 64 + t) * 2 + 1];
            }
            as_[row] = s;
            ad_[row] = d;
        }
    }
}

// standalone GEMM (layer 2)
template<int K, int N, int NH, bool A_BF16>
__global__ __launch_bounds__(256) void k_gemm_mfma(
    const void* __restrict__ Aptr, const float* __restrict__ W,
    const float* __restrict__ atts, const float* __restrict__ attd,
    unsigned short* __restrict__ C, float* __restrict__ as_, float* __restrict__ ad_,
    int M)
{
    gemm_body<K, N, NH, A_BF16>(blockIdx.x, Aptr, W, atts, attd, C, as_, ad_, M);
}

// fused: GEMM1 blocks striped 1-in-5 with CSR-scatter blocks (co-schedule MFMA + VMEM latency)
__global__ __launch_bounds__(256) void k_gemm1_scatter(
    const void* __restrict__ Aptr, const float* __restrict__ W,
    const float* __restrict__ atts, const float* __restrict__ attd,
    unsigned short* __restrict__ C, float* __restrict__ as_, float* __restrict__ ad_,
    int M,
    const int* __restrict__ src, const int* __restrict__ dst,
    int* __restrict__ writeptr, int* __restrict__ csr)
{
    int bid = blockIdx.x;
    int g = bid / 5, r = bid % 5;
    if (r == 0 && g < GB1) {
        gemm_body<128, 256, 4, false>(g, Aptr, W, atts, attd, C, as_, ad_, M);
    } else {
        int ng = (r == 0) ? g : g + 1;           // # gemm blocks with index < bid
        if (ng > GB1) ng = GB1;
        int sb = bid - ng;                        // scatter ordinal
        int i = sb * 256 + threadIdx.x;
        if (i < EE) {
            int pos = atomicAdd(&writeptr[dst[i]], 1);
            csr[pos] = src[i];
        }
    }
}

// ---------------- Layer-1 aggregation: wave/node, 4 edges/half-wave in flight ----------------
__global__ __launch_bounds__(256) void k_l1_agg(
    const unsigned short* __restrict__ xt1, const float* __restrict__ as1,
    const float* __restrict__ ad1, const int* __restrict__ rowptr,
    const int* __restrict__ csr, const float* __restrict__ b1,
    unsigned short* __restrict__ h1)
{
    int t = threadIdx.x;
    int lane = t & 63, w = t >> 6;
    int n = blockIdx.x * 4 + w;
    int beg = rowptr[n], deg = rowptr[n + 1] - beg;
    int half = lane >> 5, c = lane & 31, h = c >> 3;  // lane owns channels 8c..8c+7
    float adh = ad1[n * 4 + h];
    const char* xb = (const char*)xt1;
    const char* ab = (const char*)as1;
    unsigned co = (unsigned)(c << 4);   // byte offset of this lane's 16B within a row
    unsigned ho = (unsigned)(h << 2);   // byte offset of head within as1 row

    float acc[8] = {0.f, 0.f, 0.f, 0.f, 0.f, 0.f, 0.f, 0.f};
    float esum = 0.f;
    int j = 0;
    // main: 8 edges per wave-iter (4 per half) -> 4 independent gathers in flight
    for (; j + 8 <= deg; j += 8) {
        int p = beg + j + half * 4;
        int s0 = csr[p], s1 = csr[p + 1], s2 = csr[p + 2], s3 = csr[p + 3];
        float a0 = *(const float*)(ab + ((unsigned)(s0 << 4) + ho));
        float a1 = *(const float*)(ab + ((unsigned)(s1 << 4) + ho));
        float a2 = *(const float*)(ab + ((unsigned)(s2 << 4) + ho));
        float a3 = *(const float*)(ab + ((unsigned)(s3 << 4) + ho));
        short8 r0 = *(const short8*)(xb + ((unsigned)(s0 << 9) + co));
        short8 r1 = *(const short8*)(xb + ((unsigned)(s1 << 9) + co));
        short8 r2 = *(const short8*)(xb + ((unsigned)(s2 << 9) + co));
        short8 r3 = *(const short8*)(xb + ((unsigned)(s3 << 9) + co));
        float e0 = __expf(lrelu(a0 + adh));
        float e1 = __expf(lrelu(a1 + adh));
        float e2 = __expf(lrelu(a2 + adh));
        float e3 = __expf(lrelu(a3 + adh));
        esum += (e0 + e1) + (e2 + e3);
        #pragma unroll
        for (int k = 0; k < 8; k++)
            acc[k] += (bf2f((unsigned short)r0[k]) * e0 + bf2f((unsigned short)r1[k]) * e1)
                    + (bf2f((unsigned short)r2[k]) * e2 + bf2f((unsigned short)r3[k]) * e3);
    }
    // mid: 4 edges (2 per half)
    if (j + 4 <= deg) {
        int p = beg + j + half * 2;
        int s0 = csr[p], s1 = csr[p + 1];
        float a0 = *(const float*)(ab + ((unsigned)(s0 << 4) + ho));
        float a1 = *(const float*)(ab + ((unsigned)(s1 << 4) + ho));
        short8 r0 = *(const short8*)(xb + ((unsigned)(s0 << 9) + co));
        short8 r1 = *(const short8*)(xb + ((unsigned)(s1 << 9) + co));
        float e0 = __expf(lrelu(a0 + adh));
        float e1 = __expf(lrelu(a1 + adh));
        esum += e0 + e1;
        #pragma unroll
        for (int k = 0; k < 8; k++)
            acc[k] += bf2f((unsigned short)r0[k]) * e0 + bf2f((unsigned short)r1[k]) * e1;
        j += 4;
    }
    // tail: up to 3 edges, 1 per half per iter
    for (; j < deg; j += 2) {
        int jj = j + half;
        if (jj < deg) {
            int s = csr[beg + jj];
            float a0 = *(const float*)(ab + ((unsigned)(s << 4) + ho));
            short8 r = *(const short8*)(xb + ((unsigned)(s << 9) + co));
            float e = __expf(lrelu(a0 + adh));
            esum += e;
            #pragma unroll
            for (int k = 0; k < 8; k++) acc[k] += bf2f((unsigned short)r[k]) * e;
        }
    }
    #pragma unroll
    for (int k = 0; k < 8; k++) acc[k] += __shfl_xor(acc[k], 32);
    esum += __shfl_xor(esum, 32);
    if (half == 0) {
        float rs = 1.f / (esum + 1e-16f);
        float4 bl = *(const float4*)(b1 + c * 8);
        float4 bh = *(const float4*)(b1 + c * 8 + 4);
        float bb[8] = {bl.x, bl.y, bl.z, bl.w, bh.x, bh.y, bh.z, bh.w};
        short8 o;
        #pragma unroll
        for (int k = 0; k < 8; k++)
            o[k] = (short)f2bf(fmaxf(acc[k] * rs + bb[k], 0.f));
        *(short8*)(h1 + (size_t)n * 256 + c * 8) = o;
    }
}

// ---------------- Layer-2 aggregation + fc + sigmoid: wave/node, quarter-wave/edge ----------------
__global__ __launch_bounds__(256) void k_l2_agg(
    const unsigned short* __restrict__ xt2, const float* __restrict__ as2,
    const float* __restrict__ ad2, const int* __restrict__ rowptr,
    const int* __restrict__ csr, const float* __restrict__ b2,
    const float* __restrict__ fcw, const float* __restrict__ fcb,
    float* __restrict__ out)
{
    int t = threadIdx.x;
    int lane = t & 63, w = t >> 6;
    int n = blockIdx.x * 4 + w;
    int beg = rowptr[n], deg = rowptr[n + 1] - beg;
    int q = lane >> 4, c = lane & 15;   // lane owns channels 4c..4c+3 (8B loads)
    float adv = ad2[n];
    const char* xb = (const char*)xt2;
    unsigned co = (unsigned)(c << 3);

    float acc[4] = {0.f, 0.f, 0.f, 0.f};
    float esum = 0.f;
    int j = 0;
    // main: 8 edges per wave-iter (2 per quarter)
    for (; j + 8 <= deg; j += 8) {
        int p = beg + j + q * 2;
        int s0 = csr[p], s1 = csr[p + 1];
        float a0 = as2[s0], a1 = as2[s1];
        uint2 r0 = *(const uint2*)(xb + ((unsigned)(s0 << 7) + co));
        uint2 r1 = *(const uint2*)(xb + ((unsigned)(s1 << 7) + co));
        float e0 = __expf(lrelu(a0 + adv));
        float e1 = __expf(lrelu(a1 + adv));
        esum += e0 + e1;
        acc[0] += bf2f((unsigned short)(r0.x & 0xffff)) * e0 + bf2f((unsigned short)(r1.x & 0xffff)) * e1;
        acc[1] += bf2f((unsigned short)(r0.x >> 16)) * e0 + bf2f((unsigned short)(r1.x >> 16)) * e1;
        acc[2] += bf2f((unsigned short)(r0.y & 0xffff)) * e0 + bf2f((unsigned short)(r1.y & 0xffff)) * e1;
        acc[3] += bf2f((unsigned short)(r0.y >> 16)) * e0 + bf2f((unsigned short)(r1.y >> 16)) * e1;
    }
    // tail: 1 edge per quarter per iter
    for (; j < deg; j += 4) {
        int jj = j + q;
        if (jj < deg) {
            int s = csr[beg + jj];
            float a0 = as2[s];
            uint2 r = *(const uint2*)(xb + ((unsigned)(s << 7) + co));
            float e = __expf(lrelu(a0 + adv));
            esum += e;
            acc[0] += bf2f((unsigned short)(r.x & 0xffff)) * e;
            acc[1] += bf2f((unsigned short)(r.x >> 16)) * e;
            acc[2] += bf2f((unsigned short)(r.y & 0xffff)) * e;
            acc[3] += bf2f((unsigned short)(r.y >> 16)) * e;
        }
    }
    #pragma unroll
    for (int k = 0; k < 4; k++) {
        acc[k] += __shfl_xor(acc[k], 16);
        acc[k] += __shfl_xor(acc[k], 32);
    }
    esum += __shfl_xor(esum, 16);
    esum += __shfl_xor(esum, 32);
    float rs = 1.f / (esum + 1e-16f);
    float4 bv = *(const float4*)(b2 + c * 4);
    float4 fv = *(const float4*)(fcw + c * 4);
    float z = fmaxf(acc[0] * rs + bv.x, 0.f) * fv.x
            + fmaxf(acc[1] * rs + bv.y, 0.f) * fv.y
            + fmaxf(acc[2] * rs + bv.z, 0.f) * fv.z
            + fmaxf(acc[3] * rs + bv.w, 0.f) * fv.w;
    #pragma unroll
    for (int off = 8; off; off >>= 1) z += __shfl_xor(z, off);
    if (lane == 0) out[n] = 1.f / (1.f + __expf(-(z + fcb[0])));
}

// ---------------- launch ----------------

extern "C" void kernel_launch(void* const* d_in, const int* in_sizes, int n_in,
                              void* d_out, int out_size, void* d_ws, size_t ws_size,
                              hipStream_t stream) {
    const float* x    = (const float*)d_in[0];
    const int*   ei   = (const int*)d_in[1];
    const float* W1   = (const float*)d_in[2];
    const float* as1w = (const float*)d_in[3];
    const float* ad1w = (const float*)d_in[4];
    const float* b1   = (const float*)d_in[5];
    const float* W2   = (const float*)d_in[6];
    const float* as2w = (const float*)d_in[7];
    const float* ad2w = (const float*)d_in[8];
    const float* b2   = (const float*)d_in[9];
    const float* fcw  = (const float*)d_in[10];
    const float* fcb  = (const float*)d_in[11];
    float* out = (float*)d_out;

    const int* src = ei;
    const int* dst = ei + EE;

    char* base = (char*)d_ws;
    size_t off = 0;
    auto alloc = [&](size_t bytes) -> void* {
        void* p = base + off;
        off = (off + bytes + 255) & ~(size_t)255;
        return p;
    };
    int*   rowptr   = (int*)alloc((NN + 1) * sizeof(int));
    int*   cnt      = (int*)alloc(NN * sizeof(int));
    int*   tmp      = (int*)alloc(NN * sizeof(int));
    int*   bsum     = (int*)alloc(SG * sizeof(int));
    int*   boff     = (int*)alloc(SG * sizeof(int));
    int*   writeptr = (int*)alloc(NN * sizeof(int));
    int*   csr      = (int*)alloc(ET * sizeof(int));
    unsigned short* xt1 = (unsigned short*)alloc((size_t)NN * 256 * sizeof(unsigned short));
    unsigned short* h1  = (unsigned short*)alloc((size_t)NN * 256 * sizeof(unsigned short));
    float* as1      = (float*)alloc(NN * 4 * sizeof(float));
    float* ad1      = (float*)alloc(NN * 4 * sizeof(float));
    float* as2      = (float*)alloc(NN * sizeof(float));
    float* ad2      = (float*)alloc(NN * sizeof(float));
    unsigned short* xt2 = xt1;   // xt1 dead after l1_agg; reuse

    // CSR build (cnt=0 via memset; self-loops folded into scan arithmetic)
    hipMemsetAsync(cnt, 0, NN * sizeof(int), stream);
    k_hist<<<(EE + 255) / 256, 256, 0, stream>>>(dst, cnt);
    k_scan1<<<SG, 256, 0, stream>>>(cnt, tmp, bsum);
    k_scan2<<<1, 256, 0, stream>>>(bsum, boff);
    k_scan3_prep<<<SG, 256, 0, stream>>>(tmp, boff, rowptr, writeptr, csr);

    // GEMM1 (MFMA) striped with scatter (VMEM-latency) in one heterogeneous launch
    int fused_blocks = GB1 + (EE + 255) / 256;   // 782 + 3125 = 3907
    k_gemm1_scatter<<<fused_blocks, 256, 0, stream>>>(
        x, W1, as1w, ad1w, xt1, as1, ad1, NN, src, dst, writeptr, csr);

    k_l1_agg<<<(NN + 3) / 4, 256, 0, stream>>>(xt1, as1, ad1, rowptr, csr, b1, h1);
    k_gemm_mfma<256, 64, 1, true><<<GB1, 256, 0, stream>>>(
        h1, W2, as2w, ad2w, xt2, as2, ad2, NN);
    k_l2_agg<<<(NN + 3) / 4, 256, 0, stream>>>(xt2, as2, ad2, rowptr, csr, b2, fcw, fcb, out);
}

// Round 2
// 281.581 us; speedup vs baseline: 1.0361x; 1.0054x over previous
//
#include <hip/hip_runtime.h>
#include <hip/hip_bf16.h>

#define NN 50000
#define EE 800000
#define ET (NN + EE)   // edges incl. self-loops = 850000
#define SG ((NN + 255) / 256)   // scan blocks = 196
#define GB1 ((NN + 63) / 64)    // gemm1 / fused-l1 blocks = 782

typedef __attribute__((ext_vector_type(8))) short short8;
typedef __attribute__((ext_vector_type(4))) float f32x4;

__device__ __forceinline__ float bf2f(unsigned short u) {
    union { unsigned int i; float f; } v; v.i = ((unsigned int)u) << 16; return v.f;
}
__device__ __forceinline__ unsigned short f2bf(float f) {
    __hip_bfloat16 h = __float2bfloat16(f);
    return *reinterpret_cast<unsigned short*>(&h);
}
// lrelu(x) = max(x, 0.2x): valid for all x since 0.2x > x iff x < 0. 2 VALU ops.
__device__ __forceinline__ float lrelu(float e) { return fmaxf(e, 0.2f * e); }

// ---------------- CSR build ----------------

__global__ void k_hist(const int* __restrict__ dst, int* __restrict__ cnt) {
    int i = blockIdx.x * blockDim.x + threadIdx.x;
    if (i < EE) atomicAdd(&cnt[dst[i]], 1);
}

__global__ __launch_bounds__(256) void k_scan1(const int* __restrict__ cnt,
                                               int* __restrict__ tmp, int* __restrict__ bsum) {
    int b = blockIdx.x, t = threadIdx.x, i = b * 256 + t;
    int lane = t & 63, w = t >> 6;
    int v = (i < NN) ? cnt[i] : 0;
    int s = v;
    #pragma unroll
    for (int off = 1; off < 64; off <<= 1) {
        int u = __shfl_up(s, off);
        if (lane >= off) s += u;
    }
    __shared__ int ws[4];
    if (lane == 63) ws[w] = s;
    __syncthreads();
    if (t == 0) {
        int a = 0;
        #pragma unroll
        for (int k = 0; k < 4; k++) { int x = ws[k]; ws[k] = a; a += x; }
        bsum[b] = a;
    }
    __syncthreads();
    s += ws[w];
    if (i < NN) tmp[i] = s;
}

__global__ __launch_bounds__(256) void k_scan2(const int* __restrict__ bsum, int* __restrict__ boff) {
    int t = threadIdx.x, lane = t & 63, w = t >> 6;
    int v = (t < SG) ? bsum[t] : 0;
    int s = v;
    #pragma unroll
    for (int off = 1; off < 64; off <<= 1) {
        int u = __shfl_up(s, off);
        if (lane >= off) s += u;
    }
    __shared__ int ws[4];
    if (lane == 63) ws[w] = s;
    __syncthreads();
    if (t == 0) {
        int a = 0;
        #pragma unroll
        for (int k = 0; k < 4; k++) { int x = ws[k]; ws[k] = a; a += x; }
    }
    __syncthreads();
    s += ws[w];
    if (t < SG) boff[t] = s - v;
}

__global__ void k_scan3_prep(const int* __restrict__ tmp, const int* __restrict__ boff,
                             int* __restrict__ rowptr, int* __restrict__ writeptr,
                             int* __restrict__ csr) {
    int i = blockIdx.x * blockDim.x + threadIdx.x;
    if (i == 0) rowptr[0] = 0;
    if (i < NN) {
        int base = boff[i >> 8];
        int incl = tmp[i] + base + i + 1;
        rowptr[i + 1] = incl;
        int excl = ((i & 255) ? tmp[i - 1] + base : base) + i;   // == rowptr[i]
        csr[excl] = i;            // self-loop first
        writeptr[i] = excl + 1;
    }
}

// ---------------- MFMA bf16 GEMM body (layer-1, fused with scatter) ----------------
template<int K, int N, int NH, bool A_BF16>
__device__ __forceinline__ void gemm_body(
    int bid, const void* __restrict__ Aptr, const float* __restrict__ W,
    const float* __restrict__ atts, const float* __restrict__ attd,
    unsigned short* __restrict__ C, float* __restrict__ as_, float* __restrict__ ad_,
    int M)
{
    constexpr int KU  = K / 8;
    constexpr int KUH = KU / 2;
    constexpr int KC  = K / 32;
    constexpr int NW  = N / 4;
    constexpr int NI  = NW / 16;
    constexpr int ABYTES = 64 * KU * 16;
    constexpr int BBYTES = N * KUH * 16;
    constexpr int SMEM = ABYTES + BBYTES + (NH == 1 ? 2048 : 0);
    __shared__ char smem[SMEM];
    char* Ash = smem;
    char* Bsh = smem + ABYTES;
    unsigned short* Csh = (unsigned short*)smem;
    float* scsh = (float*)(smem + ABYTES + BBYTES);

    int t = threadIdx.x;
    int lane = t & 63, w = t >> 6;
    int colL = lane & 15, quad = lane >> 4;
    int m0 = bid * 64;

    {
        constexpr int CNT = 64 * KU / 256;
        #pragma unroll
        for (int i = 0; i < CNT; i++) {
            int v = t + 256 * i;
            int m = v / KU, u = v % KU;
            int gr = m0 + m; if (gr >= M) gr = M - 1;
            short8 val;
            if (A_BF16) {
                val = *(const short8*)((const unsigned short*)Aptr + (size_t)gr * K + u * 8);
            } else {
                const float* Af = (const float*)Aptr;
                float4 lo = *(const float4*)(Af + (size_t)gr * K + u * 8);
                float4 hi = *(const float4*)(Af + (size_t)gr * K + u * 8 + 4);
                val[0] = (short)f2bf(lo.x); val[1] = (short)f2bf(lo.y);
                val[2] = (short)f2bf(lo.z); val[3] = (short)f2bf(lo.w);
                val[4] = (short)f2bf(hi.x); val[5] = (short)f2bf(hi.y);
                val[6] = (short)f2bf(hi.z); val[7] = (short)f2bf(hi.w);
            }
            *(short8*)(Ash + ((size_t)m * KU + (u ^ (m & 7))) * 16) = val;
        }
    }

    f32x4 acc[4][NI];
    #pragma unroll
    for (int mi = 0; mi < 4; mi++)
        #pragma unroll
        for (int ni = 0; ni < NI; ni++) acc[mi][ni] = (f32x4){0.f, 0.f, 0.f, 0.f};

    #pragma unroll
    for (int kh = 0; kh < 2; kh++) {
        __syncthreads();
        {
            constexpr int CNT = N * KUH / 256;
            #pragma unroll
            for (int i = 0; i < CNT; i++) {
                int v = t + 256 * i;
                int n = v / KUH, uu = v % KUH;
                int u = kh * KUH + uu;
                float4 lo = *(const float4*)(W + (size_t)n * K + u * 8);
                float4 hi = *(const float4*)(W + (size_t)n * K + u * 8 + 4);
                short8 val;
                val[0] = (short)f2bf(lo.x); val[1] = (short)f2bf(lo.y);
                val[2] = (short)f2bf(lo.z); val[3] = (short)f2bf(lo.w);
                val[4] = (short)f2bf(hi.x); val[5] = (short)f2bf(hi.y);
                val[6] = (short)f2bf(hi.z); val[7] = (short)f2bf(hi.w);
                *(short8*)(Bsh + ((size_t)n * KUH + (uu ^ (n & 7))) * 16) = val;
            }
        }
        __syncthreads();
        #pragma unroll
        for (int kcl = 0; kcl < KC / 2; kcl++) {
            int uA = (kh * (KC / 2) + kcl) * 4 + quad;
            int uB = kcl * 4 + quad;
            short8 bfr[NI];
            #pragma unroll
            for (int ni = 0; ni < NI; ni++) {
                int n = w * NW + ni * 16 + colL;
                bfr[ni] = *(const short8*)(Bsh + ((size_t)n * KUH + (uB ^ (n & 7))) * 16);
            }
            #pragma unroll
            for (int mi = 0; mi < 4; mi++) {
                int m = mi * 16 + colL;
                short8 af = *(const short8*)(Ash + ((size_t)m * KU + (uA ^ (m & 7))) * 16);
                #pragma unroll
                for (int ni = 0; ni < NI; ni++)
                    acc[mi][ni] = __builtin_amdgcn_mfma_f32_16x16x32_bf16(af, bfr[ni], acc[mi][ni], 0, 0, 0);
            }
        }
    }
    __syncthreads();

    float asv[NI], adv[NI];
    #pragma unroll
    for (int ni = 0; ni < NI; ni++) {
        int na = (NH == 4) ? (w * 64 + ni * 16 + colL) : (w * 16 + colL);
        asv[ni] = atts[na];
        adv[ni] = attd[na];
    }
    #pragma unroll
    for (int mi = 0; mi < 4; mi++) {
        float ps[4] = {0.f, 0.f, 0.f, 0.f}, pd[4] = {0.f, 0.f, 0.f, 0.f};
        #pragma unroll
        for (int ni = 0; ni < NI; ni++)
            #pragma unroll
            for (int r = 0; r < 4; r++) {
                ps[r] += acc[mi][ni][r] * asv[ni];
                pd[r] += acc[mi][ni][r] * adv[ni];
            }
        #pragma unroll
        for (int off = 1; off < 16; off <<= 1)
            #pragma unroll
            for (int r = 0; r < 4; r++) {
                ps[r] += __shfl_xor(ps[r], off);
                pd[r] += __shfl_xor(pd[r], off);
            }
        if (colL == 0) {
            #pragma unroll
            for (int r = 0; r < 4; r++) {
                int rloc = mi * 16 + quad * 4 + r;
                if (NH == 4) {
                    int row = m0 + rloc;
                    if (row < M) {
                        as_[(size_t)row * 4 + w] = ps[r];
                        ad_[(size_t)row * 4 + w] = pd[r];
                    }
                } else {
                    scsh[(w * 64 + rloc) * 2 + 0] = ps[r];
                    scsh[(w * 64 + rloc) * 2 + 1] = pd[r];
                }
            }
        }
    }

    #pragma unroll
    for (int mi = 0; mi < 4; mi++)
        #pragma unroll
        for (int ni = 0; ni < NI; ni++)
            #pragma unroll
            for (int r = 0; r < 4; r++)
                Csh[(size_t)(mi * 16 + quad * 4 + r) * (N + 8) + w * NW + ni * 16 + colL] =
                    f2bf(acc[mi][ni][r]);
    __syncthreads();

    {
        constexpr int CNT = 64 * (N / 8) / 256;
        #pragma unroll
        for (int i = 0; i < CNT; i++) {
            int v = t + 256 * i;
            int m = v / (N / 8), u = v % (N / 8);
            int row = m0 + m;
            if (row < M)
                *(short8*)(C + (size_t)row * N + u * 8) =
                    *(const short8*)(Csh + (size_t)m * (N + 8) + u * 8);
        }
    }
    if (NH == 1 && t < 64) {
        int row = m0 + t;
        if (row < M) {
            float s = 0.f, d = 0.f;
            #pragma unroll
            for (int ww = 0; ww < 4; ww++) {
                s += scsh[(ww * 64 + t) * 2 + 0];
                d += scsh[(ww * 64 + t) * 2 + 1];
            }
            as_[row] = s;
            ad_[row] = d;
        }
    }
}

// fused: GEMM1 blocks striped 1-in-5 with CSR-scatter blocks
__global__ __launch_bounds__(256) void k_gemm1_scatter(
    const void* __restrict__ Aptr, const float* __restrict__ W,
    const float* __restrict__ atts, const float* __restrict__ attd,
    unsigned short* __restrict__ C, float* __restrict__ as_, float* __restrict__ ad_,
    int M,
    const int* __restrict__ src, const int* __restrict__ dst,
    int* __restrict__ writeptr, int* __restrict__ csr)
{
    int bid = blockIdx.x;
    int g = bid / 5, r = bid % 5;
    if (r == 0 && g < GB1) {
        gemm_body<128, 256, 4, false>(g, Aptr, W, atts, attd, C, as_, ad_, M);
    } else {
        int ng = (r == 0) ? g : g + 1;
        if (ng > GB1) ng = GB1;
        int sb = bid - ng;
        int i = sb * 256 + threadIdx.x;
        if (i < EE) {
            int pos = atomicAdd(&writeptr[dst[i]], 1);
            csr[pos] = src[i];
        }
    }
}

// ---------------- Fused layer-1 aggregation + GEMM2 ----------------
// Block = 64 nodes (4 waves x 16 nodes). h1 rows live only in LDS (MFMA A layout).
// Then 64x64 GEMM over K=256 with B-frags loaded from L2-hot W2, attention scores,
// bf16 C store. Saves the entire h1 global round-trip + gemm2 launch.
__global__ __launch_bounds__(256) void k_l1_gemm2(
    const unsigned short* __restrict__ xt1, const float* __restrict__ as1,
    const float* __restrict__ ad1, const int* __restrict__ rowptr,
    const int* __restrict__ csr, const float* __restrict__ b1,
    const float* __restrict__ W2, const float* __restrict__ atts2,
    const float* __restrict__ attd2,
    unsigned short* __restrict__ xt2, float* __restrict__ as2, float* __restrict__ ad2)
{
    __shared__ char smem[64 * 32 * 16 + 2048];   // Ash 32KB + scsh 2KB
    char* Ash = smem;
    float* scsh = (float*)(smem + 64 * 32 * 16);
    unsigned short* Csh = (unsigned short*)smem;   // overlay after MFMA reads done

    int t = threadIdx.x;
    int lane = t & 63, w = t >> 6;
    int half = lane >> 5, c = lane & 31, h = c >> 3;
    const char* xb = (const char*)xt1;
    const char* ab = (const char*)as1;
    unsigned co = (unsigned)(c << 4);
    unsigned ho = (unsigned)(h << 2);
    int m0 = blockIdx.x * 64;

    // ---- phase 1: aggregate 16 nodes per wave into Ash (A-swizzle layout) ----
    #pragma unroll 1
    for (int i = 0; i < 16; i++) {
        int m = w * 16 + i;
        int n = m0 + m;
        float acc[8] = {0.f, 0.f, 0.f, 0.f, 0.f, 0.f, 0.f, 0.f};
        float esum = 0.f;
        if (n < NN) {
            int beg = rowptr[n], deg = rowptr[n + 1] - beg;
            float adh = ad1[(n << 2) + h];
            int j = 0;
            if (deg >= 8) {
                // prologue: group 0 indices + atts + gathers
                int p = beg + half * 4;
                int s0 = csr[p], s1 = csr[p + 1], s2 = csr[p + 2], s3 = csr[p + 3];
                float a0 = *(const float*)(ab + ((unsigned)(s0 << 4) + ho));
                float a1 = *(const float*)(ab + ((unsigned)(s1 << 4) + ho));
                float a2 = *(const float*)(ab + ((unsigned)(s2 << 4) + ho));
                float a3 = *(const float*)(ab + ((unsigned)(s3 << 4) + ho));
                short8 r0 = *(const short8*)(xb + ((unsigned)(s0 << 9) + co));
                short8 r1 = *(const short8*)(xb + ((unsigned)(s1 << 9) + co));
                short8 r2 = *(const short8*)(xb + ((unsigned)(s2 << 9) + co));
                short8 r3 = *(const short8*)(xb + ((unsigned)(s3 << 9) + co));
                // steady state: prefetch group j+8 while computing group j
                for (; j + 16 <= deg; j += 8) {
                    int p2 = beg + j + 8 + half * 4;
                    int u0 = csr[p2], u1 = csr[p2 + 1], u2 = csr[p2 + 2], u3 = csr[p2 + 3];
                    float f0 = *(const float*)(ab + ((unsigned)(u0 << 4) + ho));
                    float f1 = *(const float*)(ab + ((unsigned)(u1 << 4) + ho));
                    float f2 = *(const float*)(ab + ((unsigned)(u2 << 4) + ho));
                    float f3 = *(const float*)(ab + ((unsigned)(u3 << 4) + ho));
                    short8 q0 = *(const short8*)(xb + ((unsigned)(u0 << 9) + co));
                    short8 q1 = *(const short8*)(xb + ((unsigned)(u1 << 9) + co));
                    short8 q2 = *(const short8*)(xb + ((unsigned)(u2 << 9) + co));
                    short8 q3 = *(const short8*)(xb + ((unsigned)(u3 << 9) + co));
                    float e0 = __expf(lrelu(a0 + adh));
                    float e1 = __expf(lrelu(a1 + adh));
                    float e2 = __expf(lrelu(a2 + adh));
                    float e3 = __expf(lrelu(a3 + adh));
                    esum += (e0 + e1) + (e2 + e3);
                    #pragma unroll
                    for (int k = 0; k < 8; k++)
                        acc[k] += (bf2f((unsigned short)r0[k]) * e0 + bf2f((unsigned short)r1[k]) * e1)
                                + (bf2f((unsigned short)r2[k]) * e2 + bf2f((unsigned short)r3[k]) * e3);
                    a0 = f0; a1 = f1; a2 = f2; a3 = f3;
                    r0 = q0; r1 = q1; r2 = q2; r3 = q3;
                }
                // drain last loaded group
                {
                    float e0 = __expf(lrelu(a0 + adh));
                    float e1 = __expf(lrelu(a1 + adh));
                    float e2 = __expf(lrelu(a2 + adh));
                    float e3 = __expf(lrelu(a3 + adh));
                    esum += (e0 + e1) + (e2 + e3);
                    #pragma unroll
                    for (int k = 0; k < 8; k++)
                        acc[k] += (bf2f((unsigned short)r0[k]) * e0 + bf2f((unsigned short)r1[k]) * e1)
                                + (bf2f((unsigned short)r2[k]) * e2 + bf2f((unsigned short)r3[k]) * e3);
                    j += 8;
                }
            }
            if (j + 4 <= deg) {
                int p = beg + j + half * 2;
                int s0 = csr[p], s1 = csr[p + 1];
                float a0 = *(const float*)(ab + ((unsigned)(s0 << 4) + ho));
                float a1 = *(const float*)(ab + ((unsigned)(s1 << 4) + ho));
                short8 r0 = *(const short8*)(xb + ((unsigned)(s0 << 9) + co));
                short8 r1 = *(const short8*)(xb + ((unsigned)(s1 << 9) + co));
                float e0 = __expf(lrelu(a0 + adh));
                float e1 = __expf(lrelu(a1 + adh));
                esum += e0 + e1;
                #pragma unroll
                for (int k = 0; k < 8; k++)
                    acc[k] += bf2f((unsigned short)r0[k]) * e0 + bf2f((unsigned short)r1[k]) * e1;
                j += 4;
            }
            for (; j < deg; j += 2) {
                int jj = j + half;
                if (jj < deg) {
                    int s = csr[beg + jj];
                    float a0 = *(const float*)(ab + ((unsigned)(s << 4) + ho));
                    short8 r = *(const short8*)(xb + ((unsigned)(s << 9) + co));
                    float e = __expf(lrelu(a0 + adh));
                    esum += e;
                    #pragma unroll
                    for (int k = 0; k < 8; k++) acc[k] += bf2f((unsigned short)r[k]) * e;
                }
            }
        }
        #pragma unroll
        for (int k = 0; k < 8; k++) acc[k] += __shfl_xor(acc[k], 32);
        esum += __shfl_xor(esum, 32);
        if (half == 0) {
            short8 o;
            if (n < NN) {
                float rs = 1.f / (esum + 1e-16f);
                float4 bl = *(const float4*)(b1 + c * 8);
                float4 bh = *(const float4*)(b1 + c * 8 + 4);
                float bb[8] = {bl.x, bl.y, bl.z, bl.w, bh.x, bh.y, bh.z, bh.w};
                #pragma unroll
                for (int k = 0; k < 8; k++)
                    o[k] = (short)f2bf(fmaxf(acc[k] * rs + bb[k], 0.f));
            } else {
                #pragma unroll
                for (int k = 0; k < 8; k++) o[k] = 0;
            }
            *(short8*)(Ash + (((unsigned)(m * 32 + (c ^ (m & 7)))) << 4)) = o;
        }
    }

    // ---- phase 2: B fragments from global W2 (64x256 f32, L2-hot) ----
    int colL = lane & 15, quad = lane >> 4;
    short8 bf[8];
    {
        int nrow = w * 16 + colL;
        const float* wp = W2 + nrow * 256;
        #pragma unroll
        for (int kc = 0; kc < 8; kc++) {
            const float* p = wp + (kc * 4 + quad) * 8;
            float4 lo = *(const float4*)p;
            float4 hi = *(const float4*)(p + 4);
            short8 v;
            v[0] = (short)f2bf(lo.x); v[1] = (short)f2bf(lo.y);
            v[2] = (short)f2bf(lo.z); v[3] = (short)f2bf(lo.w);
            v[4] = (short)f2bf(hi.x); v[5] = (short)f2bf(hi.y);
            v[6] = (short)f2bf(hi.z); v[7] = (short)f2bf(hi.w);
            bf[kc] = v;
        }
    }
    __syncthreads();   // all Ash rows written

    // ---- phase 3: 64x64 MFMA over K=256 ----
    f32x4 acc2[4];
    #pragma unroll
    for (int mi = 0; mi < 4; mi++) acc2[mi] = (f32x4){0.f, 0.f, 0.f, 0.f};
    #pragma unroll
    for (int kc = 0; kc < 8; kc++) {
        int uA = kc * 4 + quad;
        #pragma unroll
        for (int mi = 0; mi < 4; mi++) {
            int mm = mi * 16 + colL;
            short8 af = *(const short8*)(Ash + (((unsigned)(mm * 32 + (uA ^ (mm & 7)))) << 4));
            acc2[mi] = __builtin_amdgcn_mfma_f32_16x16x32_bf16(af, bf[kc], acc2[mi], 0, 0, 0);
        }
    }

    // ---- phase 4: attention partial sums (NH=1) ----
    {
        float asv = atts2[w * 16 + colL];
        float adv = attd2[w * 16 + colL];
        #pragma unroll
        for (int mi = 0; mi < 4; mi++) {
            float ps[4], pd[4];
            #pragma unroll
            for (int r = 0; r < 4; r++) { ps[r] = acc2[mi][r] * asv; pd[r] = acc2[mi][r] * adv; }
            #pragma unroll
            for (int off = 1; off < 16; off <<= 1)
                #pragma unroll
                for (int r = 0; r < 4; r++) {
                    ps[r] += __shfl_xor(ps[r], off);
                    pd[r] += __shfl_xor(pd[r], off);
                }
            if (colL == 0) {
                #pragma unroll
                for (int r = 0; r < 4; r++) {
                    int rloc = mi * 16 + quad * 4 + r;
                    scsh[(w * 64 + rloc) * 2 + 0] = ps[r];
                    scsh[(w * 64 + rloc) * 2 + 1] = pd[r];
                }
            }
        }
    }
    __syncthreads();   // Ash reads done (overlay safe), scsh complete

    // ---- phase 5: C repack (bf16) + score reduce + coalesced store ----
    #pragma unroll
    for (int mi = 0; mi < 4; mi++)
        #pragma unroll
        for (int r = 0; r < 4; r++)
            Csh[(size_t)(mi * 16 + quad * 4 + r) * 72 + w * 16 + colL] = f2bf(acc2[mi][r]);
    if (t < 64) {
        int row = m0 + t;
        if (row < NN) {
            float s = 0.f, d = 0.f;
            #pragma unroll
            for (int ww = 0; ww < 4; ww++) {
                s += scsh[(ww * 64 + t) * 2 + 0];
                d += scsh[(ww * 64 + t) * 2 + 1];
            }
            as2[row] = s;
            ad2[row] = d;
        }
    }
    __syncthreads();
    #pragma unroll
    for (int i2 = 0; i2 < 2; i2++) {
        int v = t + 256 * i2;
        int mm = v >> 3, u = v & 7;
        int row = m0 + mm;
        if (row < NN)
            *(short8*)(xt2 + (size_t)row * 64 + u * 8) =
                *(const short8*)(Csh + (size_t)mm * 72 + u * 8);
    }
}

// ---------------- Layer-2 aggregation + fc + sigmoid: pipelined quarter-wave/edge ----------------
__global__ __launch_bounds__(256) void k_l2_agg(
    const unsigned short* __restrict__ xt2, const float* __restrict__ as2,
    const float* __restrict__ ad2, const int* __restrict__ rowptr,
    const int* __restrict__ csr, const float* __restrict__ b2,
    const float* __restrict__ fcw, const float* __restrict__ fcb,
    float* __restrict__ out)
{
    int t = threadIdx.x;
    int lane = t & 63, w = t >> 6;
    int n = blockIdx.x * 4 + w;
    int beg = rowptr[n], deg = rowptr[n + 1] - beg;
    int q = lane >> 4, c = lane & 15;   // lane owns channels 4c..4c+3 (8B loads)
    float adv = ad2[n];
    const char* xb = (const char*)xt2;
    unsigned co = (unsigned)(c << 3);

    float acc[4] = {0.f, 0.f, 0.f, 0.f};
    float esum = 0.f;
    int j = 0;
    if (deg >= 8) {
        int p = beg + q * 2;
        int s0 = csr[p], s1 = csr[p + 1];
        float a0 = as2[s0], a1 = as2[s1];
        uint2 r0 = *(const uint2*)(xb + ((unsigned)(s0 << 7) + co));
        uint2 r1 = *(const uint2*)(xb + ((unsigned)(s1 << 7) + co));
        for (; j + 16 <= deg; j += 8) {
            int p2 = beg + j + 8 + q * 2;
            int u0 = csr[p2], u1 = csr[p2 + 1];
            float f0 = as2[u0], f1 = as2[u1];
            uint2 q0 = *(const uint2*)(xb + ((unsigned)(u0 << 7) + co));
            uint2 q1 = *(const uint2*)(xb + ((unsigned)(u1 << 7) + co));
            float e0 = __expf(lrelu(a0 + adv));
            float e1 = __expf(lrelu(a1 + adv));
            esum += e0 + e1;
            acc[0] += bf2f((unsigned short)(r0.x & 0xffff)) * e0 + bf2f((unsigned short)(r1.x & 0xffff)) * e1;
            acc[1] += bf2f((unsigned short)(r0.x >> 16)) * e0 + bf2f((unsigned short)(r1.x >> 16)) * e1;
            acc[2] += bf2f((unsigned short)(r0.y & 0xffff)) * e0 + bf2f((unsigned short)(r1.y & 0xffff)) * e1;
            acc[3] += bf2f((unsigned short)(r0.y >> 16)) * e0 + bf2f((unsigned short)(r1.y >> 16)) * e1;
            a0 = f0; a1 = f1; r0 = q0; r1 = q1;
        }
        {
            float e0 = __expf(lrelu(a0 + adv));
            float e1 = __expf(lrelu(a1 + adv));
            esum += e0 + e1;
            acc[0] += bf2f((unsigned short)(r0.x & 0xffff)) * e0 + bf2f((unsigned short)(r1.x & 0xffff)) * e1;
            acc[1] += bf2f((unsigned short)(r0.x >> 16)) * e0 + bf2f((unsigned short)(r1.x >> 16)) * e1;
            acc[2] += bf2f((unsigned short)(r0.y & 0xffff)) * e0 + bf2f((unsigned short)(r1.y & 0xffff)) * e1;
            acc[3] += bf2f((unsigned short)(r0.y >> 16)) * e0 + bf2f((unsigned short)(r1.y >> 16)) * e1;
            j += 8;
        }
    }
    for (; j < deg; j += 4) {
        int jj = j + q;
        if (jj < deg) {
            int s = csr[beg + jj];
            float a0 = as2[s];
            uint2 r = *(const uint2*)(xb + ((unsigned)(s << 7) + co));
            float e = __expf(lrelu(a0 + adv));
            esum += e;
            acc[0] += bf2f((unsigned short)(r.x & 0xffff)) * e;
            acc[1] += bf2f((unsigned short)(r.x >> 16)) * e;
            acc[2] += bf2f((unsigned short)(r.y & 0xffff)) * e;
            acc[3] += bf2f((unsigned short)(r.y >> 16)) * e;
        }
    }
    #pragma unroll
    for (int k = 0; k < 4; k++) {
        acc[k] += __shfl_xor(acc[k], 16);
        acc[k] += __shfl_xor(acc[k], 32);
    }
    esum += __shfl_xor(esum, 16);
    esum += __shfl_xor(esum, 32);
    float rs = 1.f / (esum + 1e-16f);
    float4 bv = *(const float4*)(b2 + c * 4);
    float4 fv = *(const float4*)(fcw + c * 4);
    float z = fmaxf(acc[0] * rs + bv.x, 0.f) * fv.x
            + fmaxf(acc[1] * rs + bv.y, 0.f) * fv.y
            + fmaxf(acc[2] * rs + bv.z, 0.f) * fv.z
            + fmaxf(acc[3] * rs + bv.w, 0.f) * fv.w;
    #pragma unroll
    for (int off = 8; off; off >>= 1) z += __shfl_xor(z, off);
    if (lane == 0) out[n] = 1.f / (1.f + __expf(-(z + fcb[0])));
}

// ---------------- launch ----------------

extern "C" void kernel_launch(void* const* d_in, const int* in_sizes, int n_in,
                              void* d_out, int out_size, void* d_ws, size_t ws_size,
                              hipStream_t stream) {
    const float* x    = (const float*)d_in[0];
    const int*   ei   = (const int*)d_in[1];
    const float* W1   = (const float*)d_in[2];
    const float* as1w = (const float*)d_in[3];
    const float* ad1w = (const float*)d_in[4];
    const float* b1   = (const float*)d_in[5];
    const float* W2   = (const float*)d_in[6];
    const float* as2w = (const float*)d_in[7];
    const float* ad2w = (const float*)d_in[8];
    const float* b2   = (const float*)d_in[9];
    const float* fcw  = (const float*)d_in[10];
    const float* fcb  = (const float*)d_in[11];
    float* out = (float*)d_out;

    const int* src = ei;
    const int* dst = ei + EE;

    char* base = (char*)d_ws;
    size_t off = 0;
    auto alloc = [&](size_t bytes) -> void* {
        void* p = base + off;
        off = (off + bytes + 255) & ~(size_t)255;
        return p;
    };
    int*   rowptr   = (int*)alloc((NN + 1) * sizeof(int));
    int*   cnt      = (int*)alloc(NN * sizeof(int));
    int*   tmp      = (int*)alloc(NN * sizeof(int));
    int*   bsum     = (int*)alloc(SG * sizeof(int));
    int*   boff     = (int*)alloc(SG * sizeof(int));
    int*   writeptr = (int*)alloc(NN * sizeof(int));
    int*   csr      = (int*)alloc(ET * sizeof(int));
    unsigned short* xt1 = (unsigned short*)alloc((size_t)NN * 256 * sizeof(unsigned short));
    unsigned short* xt2 = (unsigned short*)alloc((size_t)NN * 64 * sizeof(unsigned short));
    float* as1      = (float*)alloc(NN * 4 * sizeof(float));
    float* ad1      = (float*)alloc(NN * 4 * sizeof(float));
    float* as2      = (float*)alloc(NN * sizeof(float));
    float* ad2      = (float*)alloc(NN * sizeof(float));

    // CSR build
    hipMemsetAsync(cnt, 0, NN * sizeof(int), stream);
    k_hist<<<(EE + 255) / 256, 256, 0, stream>>>(dst, cnt);
    k_scan1<<<SG, 256, 0, stream>>>(cnt, tmp, bsum);
    k_scan2<<<1, 256, 0, stream>>>(bsum, boff);
    k_scan3_prep<<<SG, 256, 0, stream>>>(tmp, boff, rowptr, writeptr, csr);

    // GEMM1 (MFMA) striped with scatter in one heterogeneous launch
    int fused_blocks = GB1 + (EE + 255) / 256;   // 782 + 3125 = 3907
    k_gemm1_scatter<<<fused_blocks, 256, 0, stream>>>(
        x, W1, as1w, ad1w, xt1, as1, ad1, NN, src, dst, writeptr, csr);

    // fused layer-1 aggregation + GEMM2 (h1 never touches global)
    k_l1_gemm2<<<GB1, 256, 0, stream>>>(
        xt1, as1, ad1, rowptr, csr, b1, W2, as2w, ad2w, xt2, as2, ad2);

    k_l2_agg<<<(NN + 3) / 4, 256, 0, stream>>>(xt2, as2, ad2, rowptr, csr, b2, fcw, fcb, out);
}

// Round 3
// 280.041 us; speedup vs baseline: 1.0418x; 1.0055x over previous
//
#include <hip/hip_runtime.h>
#include <hip/hip_bf16.h>

#define NN 50000
#define EE 800000
#define ET (NN + EE)   // edges incl. self-loops = 850000
#define SG ((NN + 255) / 256)   // scan blocks = 196
#define GB1 ((NN + 63) / 64)    // gemm1 blocks = 782
#define NB 32                   // nodes per fused-l1 block
#define GB2 ((NN + NB - 1) / NB)  // fused-l1 blocks = 1563

typedef __attribute__((ext_vector_type(8))) short short8;
typedef __attribute__((ext_vector_type(4))) short short4b;
typedef __attribute__((ext_vector_type(4))) float f32x4;

__device__ __forceinline__ float bf2f(unsigned short u) {
    union { unsigned int i; float f; } v; v.i = ((unsigned int)u) << 16; return v.f;
}
__device__ __forceinline__ unsigned short f2bf(float f) {
    __hip_bfloat16 h = __float2bfloat16(f);
    return *reinterpret_cast<unsigned short*>(&h);
}
// lrelu(x) = max(x, 0.2x): valid for all x since 0.2x > x iff x < 0. 2 VALU ops.
__device__ __forceinline__ float lrelu(float e) { return fmaxf(e, 0.2f * e); }

// ---------------- CSR build (+ W2 bf16 pre-convert in first 16 blocks) ----------------

__global__ void k_hist(const int* __restrict__ dst, int* __restrict__ cnt,
                       const float* __restrict__ W2, unsigned short* __restrict__ w2b) {
    int t = threadIdx.x;
    if (blockIdx.x < 16) {
        int j = blockIdx.x * 256 + t;       // 4096 threads x 4 elems = 16384 = 64*256
        float4 v = *(const float4*)(W2 + j * 4);
        short4b o;
        o[0] = (short)f2bf(v.x); o[1] = (short)f2bf(v.y);
        o[2] = (short)f2bf(v.z); o[3] = (short)f2bf(v.w);
        *(short4b*)(w2b + j * 4) = o;
    }
    int i = blockIdx.x * blockDim.x + t;
    if (i < EE) atomicAdd(&cnt[dst[i]], 1);
}

__global__ __launch_bounds__(256) void k_scan1(const int* __restrict__ cnt,
                                               int* __restrict__ tmp, int* __restrict__ bsum) {
    int b = blockIdx.x, t = threadIdx.x, i = b * 256 + t;
    int lane = t & 63, w = t >> 6;
    int v = (i < NN) ? cnt[i] : 0;
    int s = v;
    #pragma unroll
    for (int off = 1; off < 64; off <<= 1) {
        int u = __shfl_up(s, off);
        if (lane >= off) s += u;
    }
    __shared__ int ws[4];
    if (lane == 63) ws[w] = s;
    __syncthreads();
    if (t == 0) {
        int a = 0;
        #pragma unroll
        for (int k = 0; k < 4; k++) { int x = ws[k]; ws[k] = a; a += x; }
        bsum[b] = a;
    }
    __syncthreads();
    s += ws[w];
    if (i < NN) tmp[i] = s;
}

__global__ __launch_bounds__(256) void k_scan2(const int* __restrict__ bsum, int* __restrict__ boff) {
    int t = threadIdx.x, lane = t & 63, w = t >> 6;
    int v = (t < SG) ? bsum[t] : 0;
    int s = v;
    #pragma unroll
    for (int off = 1; off < 64; off <<= 1) {
        int u = __shfl_up(s, off);
        if (lane >= off) s += u;
    }
    __shared__ int ws[4];
    if (lane == 63) ws[w] = s;
    __syncthreads();
    if (t == 0) {
        int a = 0;
        #pragma unroll
        for (int k = 0; k < 4; k++) { int x = ws[k]; ws[k] = a; a += x; }
    }
    __syncthreads();
    s += ws[w];
    if (t < SG) boff[t] = s - v;
}

__global__ void k_scan3_prep(const int* __restrict__ tmp, const int* __restrict__ boff,
                             int* __restrict__ rowptr, int* __restrict__ writeptr,
                             int* __restrict__ csr) {
    int i = blockIdx.x * blockDim.x + threadIdx.x;
    if (i == 0) rowptr[0] = 0;
    if (i < NN) {
        int base = boff[i >> 8];
        int incl = tmp[i] + base + i + 1;
        rowptr[i + 1] = incl;
        int excl = ((i & 255) ? tmp[i - 1] + base : base) + i;   // == rowptr[i]
        csr[excl] = i;            // self-loop first
        writeptr[i] = excl + 1;
    }
}

// ---------------- MFMA bf16 GEMM body (layer-1, fused with scatter) ----------------
template<int K, int N, int NH, bool A_BF16>
__device__ __forceinline__ void gemm_body(
    int bid, const void* __restrict__ Aptr, const float* __restrict__ W,
    const float* __restrict__ atts, const float* __restrict__ attd,
    unsigned short* __restrict__ C, float* __restrict__ as_, float* __restrict__ ad_,
    int M)
{
    constexpr int KU  = K / 8;
    constexpr int KUH = KU / 2;
    constexpr int KC  = K / 32;
    constexpr int NW  = N / 4;
    constexpr int NI  = NW / 16;
    constexpr int ABYTES = 64 * KU * 16;
    constexpr int BBYTES = N * KUH * 16;
    constexpr int SMEM = ABYTES + BBYTES + (NH == 1 ? 2048 : 0);
    __shared__ char smem[SMEM];
    char* Ash = smem;
    char* Bsh = smem + ABYTES;
    unsigned short* Csh = (unsigned short*)smem;
    float* scsh = (float*)(smem + ABYTES + BBYTES);

    int t = threadIdx.x;
    int lane = t & 63, w = t >> 6;
    int colL = lane & 15, quad = lane >> 4;
    int m0 = bid * 64;

    {
        constexpr int CNT = 64 * KU / 256;
        #pragma unroll
        for (int i = 0; i < CNT; i++) {
            int v = t + 256 * i;
            int m = v / KU, u = v % KU;
            int gr = m0 + m; if (gr >= M) gr = M - 1;
            short8 val;
            if (A_BF16) {
                val = *(const short8*)((const unsigned short*)Aptr + (size_t)gr * K + u * 8);
            } else {
                const float* Af = (const float*)Aptr;
                float4 lo = *(const float4*)(Af + (size_t)gr * K + u * 8);
                float4 hi = *(const float4*)(Af + (size_t)gr * K + u * 8 + 4);
                val[0] = (short)f2bf(lo.x); val[1] = (short)f2bf(lo.y);
                val[2] = (short)f2bf(lo.z); val[3] = (short)f2bf(lo.w);
                val[4] = (short)f2bf(hi.x); val[5] = (short)f2bf(hi.y);
                val[6] = (short)f2bf(hi.z); val[7] = (short)f2bf(hi.w);
            }
            *(short8*)(Ash + ((size_t)m * KU + (u ^ (m & 7))) * 16) = val;
        }
    }

    f32x4 acc[4][NI];
    #pragma unroll
    for (int mi = 0; mi < 4; mi++)
        #pragma unroll
        for (int ni = 0; ni < NI; ni++) acc[mi][ni] = (f32x4){0.f, 0.f, 0.f, 0.f};

    #pragma unroll
    for (int kh = 0; kh < 2; kh++) {
        __syncthreads();
        {
            constexpr int CNT = N * KUH / 256;
            #pragma unroll
            for (int i = 0; i < CNT; i++) {
                int v = t + 256 * i;
                int n = v / KUH, uu = v % KUH;
                int u = kh * KUH + uu;
                float4 lo = *(const float4*)(W + (size_t)n * K + u * 8);
                float4 hi = *(const float4*)(W + (size_t)n * K + u * 8 + 4);
                short8 val;
                val[0] = (short)f2bf(lo.x); val[1] = (short)f2bf(lo.y);
                val[2] = (short)f2bf(lo.z); val[3] = (short)f2bf(lo.w);
                val[4] = (short)f2bf(hi.x); val[5] = (short)f2bf(hi.y);
                val[6] = (short)f2bf(hi.z); val[7] = (short)f2bf(hi.w);
                *(short8*)(Bsh + ((size_t)n * KUH + (uu ^ (n & 7))) * 16) = val;
            }
        }
        __syncthreads();
        #pragma unroll
        for (int kcl = 0; kcl < KC / 2; kcl++) {
            int uA = (kh * (KC / 2) + kcl) * 4 + quad;
            int uB = kcl * 4 + quad;
            short8 bfr[NI];
            #pragma unroll
            for (int ni = 0; ni < NI; ni++) {
                int n = w * NW + ni * 16 + colL;
                bfr[ni] = *(const short8*)(Bsh + ((size_t)n * KUH + (uB ^ (n & 7))) * 16);
            }
            #pragma unroll
            for (int mi = 0; mi < 4; mi++) {
                int m = mi * 16 + colL;
                short8 af = *(const short8*)(Ash + ((size_t)m * KU + (uA ^ (m & 7))) * 16);
                #pragma unroll
                for (int ni = 0; ni < NI; ni++)
                    acc[mi][ni] = __builtin_amdgcn_mfma_f32_16x16x32_bf16(af, bfr[ni], acc[mi][ni], 0, 0, 0);
            }
        }
    }
    __syncthreads();

    float asv[NI], adv[NI];
    #pragma unroll
    for (int ni = 0; ni < NI; ni++) {
        int na = (NH == 4) ? (w * 64 + ni * 16 + colL) : (w * 16 + colL);
        asv[ni] = atts[na];
        adv[ni] = attd[na];
    }
    #pragma unroll
    for (int mi = 0; mi < 4; mi++) {
        float ps[4] = {0.f, 0.f, 0.f, 0.f}, pd[4] = {0.f, 0.f, 0.f, 0.f};
        #pragma unroll
        for (int ni = 0; ni < NI; ni++)
            #pragma unroll
            for (int r = 0; r < 4; r++) {
                ps[r] += acc[mi][ni][r] * asv[ni];
                pd[r] += acc[mi][ni][r] * adv[ni];
            }
        #pragma unroll
        for (int off = 1; off < 16; off <<= 1)
            #pragma unroll
            for (int r = 0; r < 4; r++) {
                ps[r] += __shfl_xor(ps[r], off);
                pd[r] += __shfl_xor(pd[r], off);
            }
        if (colL == 0) {
            #pragma unroll
            for (int r = 0; r < 4; r++) {
                int rloc = mi * 16 + quad * 4 + r;
                if (NH == 4) {
                    int row = m0 + rloc;
                    if (row < M) {
                        as_[(size_t)row * 4 + w] = ps[r];
                        ad_[(size_t)row * 4 + w] = pd[r];
                    }
                } else {
                    scsh[(w * 64 + rloc) * 2 + 0] = ps[r];
                    scsh[(w * 64 + rloc) * 2 + 1] = pd[r];
                }
            }
        }
    }

    #pragma unroll
    for (int mi = 0; mi < 4; mi++)
        #pragma unroll
        for (int ni = 0; ni < NI; ni++)
            #pragma unroll
            for (int r = 0; r < 4; r++)
                Csh[(size_t)(mi * 16 + quad * 4 + r) * (N + 8) + w * NW + ni * 16 + colL] =
                    f2bf(acc[mi][ni][r]);
    __syncthreads();

    {
        constexpr int CNT = 64 * (N / 8) / 256;
        #pragma unroll
        for (int i = 0; i < CNT; i++) {
            int v = t + 256 * i;
            int m = v / (N / 8), u = v % (N / 8);
            int row = m0 + m;
            if (row < M)
                *(short8*)(C + (size_t)row * N + u * 8) =
                    *(const short8*)(Csh + (size_t)m * (N + 8) + u * 8);
        }
    }
    if (NH == 1 && t < 64) {
        int row = m0 + t;
        if (row < M) {
            float s = 0.f, d = 0.f;
            #pragma unroll
            for (int ww = 0; ww < 4; ww++) {
                s += scsh[(ww * 64 + t) * 2 + 0];
                d += scsh[(ww * 64 + t) * 2 + 1];
            }
            as_[row] = s;
            ad_[row] = d;
        }
    }
}

// fused: GEMM1 blocks striped 1-in-5 with CSR-scatter blocks
__global__ __launch_bounds__(256) void k_gemm1_scatter(
    const void* __restrict__ Aptr, const float* __restrict__ W,
    const float* __restrict__ atts, const float* __restrict__ attd,
    unsigned short* __restrict__ C, float* __restrict__ as_, float* __restrict__ ad_,
    int M,
    const int* __restrict__ src, const int* __restrict__ dst,
    int* __restrict__ writeptr, int* __restrict__ csr)
{
    int bid = blockIdx.x;
    int g = bid / 5, r = bid % 5;
    if (r == 0 && g < GB1) {
        gemm_body<128, 256, 4, false>(g, Aptr, W, atts, attd, C, as_, ad_, M);
    } else {
        int ng = (r == 0) ? g : g + 1;
        if (ng > GB1) ng = GB1;
        int sb = bid - ng;
        int i = sb * 256 + threadIdx.x;
        if (i < EE) {
            int pos = atomicAdd(&writeptr[dst[i]], 1);
            csr[pos] = src[i];
        }
    }
}

// ---------------- Fused layer-1 aggregation + GEMM2, 32 nodes/block ----------------
// Block = 32 nodes (4 waves x 8 nodes). h1 rows live only in LDS (MFMA A layout).
// Grid 1563 -> ~6 blocks/CU; LDS 17.4KB keeps occupancy grid-bound, not LDS-bound.
__global__ __launch_bounds__(256) void k_l1_gemm2(
    const unsigned short* __restrict__ xt1, const float* __restrict__ as1,
    const float* __restrict__ ad1, const int* __restrict__ rowptr,
    const int* __restrict__ csr, const float* __restrict__ b1,
    const unsigned short* __restrict__ w2b, const float* __restrict__ atts2,
    const float* __restrict__ attd2,
    unsigned short* __restrict__ xt2, float* __restrict__ as2, float* __restrict__ ad2)
{
    __shared__ char smem[NB * 32 * 16 + 1024];   // Ash 16KB + scsh 1KB
    char* Ash = smem;
    float* scsh = (float*)(smem + NB * 32 * 16);
    unsigned short* Csh = (unsigned short*)smem;   // overlay after MFMA reads done

    int t = threadIdx.x;
    int lane = t & 63, w = t >> 6;
    int half = lane >> 5, c = lane & 31, h = c >> 3;
    const char* xb = (const char*)xt1;
    const char* ab = (const char*)as1;
    unsigned co = (unsigned)(c << 4);
    unsigned ho = (unsigned)(h << 2);
    int m0 = blockIdx.x * NB;

    // ---- phase 1: aggregate 8 nodes per wave into Ash (A-swizzle layout) ----
    #pragma unroll 1
    for (int i = 0; i < 8; i++) {
        int m = w * 8 + i;
        int n = m0 + m;
        float acc[8] = {0.f, 0.f, 0.f, 0.f, 0.f, 0.f, 0.f, 0.f};
        float esum = 0.f;
        if (n < NN) {
            int beg = rowptr[n], deg = rowptr[n + 1] - beg;
            float adh = ad1[(n << 2) + h];
            int j = 0;
            if (deg >= 8) {
                int p = beg + half * 4;
                int s0 = csr[p], s1 = csr[p + 1], s2 = csr[p + 2], s3 = csr[p + 3];
                float a0 = *(const float*)(ab + ((unsigned)(s0 << 4) + ho));
                float a1 = *(const float*)(ab + ((unsigned)(s1 << 4) + ho));
                float a2 = *(const float*)(ab + ((unsigned)(s2 << 4) + ho));
                float a3 = *(const float*)(ab + ((unsigned)(s3 << 4) + ho));
                short8 r0 = *(const short8*)(xb + ((unsigned)(s0 << 9) + co));
                short8 r1 = *(const short8*)(xb + ((unsigned)(s1 << 9) + co));
                short8 r2 = *(const short8*)(xb + ((unsigned)(s2 << 9) + co));
                short8 r3 = *(const short8*)(xb + ((unsigned)(s3 << 9) + co));
                for (; j + 16 <= deg; j += 8) {
                    int p2 = beg + j + 8 + half * 4;
                    int u0 = csr[p2], u1 = csr[p2 + 1], u2 = csr[p2 + 2], u3 = csr[p2 + 3];
                    float f0 = *(const float*)(ab + ((unsigned)(u0 << 4) + ho));
                    float f1 = *(const float*)(ab + ((unsigned)(u1 << 4) + ho));
                    float f2 = *(const float*)(ab + ((unsigned)(u2 << 4) + ho));
                    float f3 = *(const float*)(ab + ((unsigned)(u3 << 4) + ho));
                    short8 q0 = *(const short8*)(xb + ((unsigned)(u0 << 9) + co));
                    short8 q1 = *(const short8*)(xb + ((unsigned)(u1 << 9) + co));
                    short8 q2 = *(const short8*)(xb + ((unsigned)(u2 << 9) + co));
                    short8 q3 = *(const short8*)(xb + ((unsigned)(u3 << 9) + co));
                    float e0 = __expf(lrelu(a0 + adh));
                    float e1 = __expf(lrelu(a1 + adh));
                    float e2 = __expf(lrelu(a2 + adh));
                    float e3 = __expf(lrelu(a3 + adh));
                    esum += (e0 + e1) + (e2 + e3);
                    #pragma unroll
                    for (int k = 0; k < 8; k++)
                        acc[k] += (bf2f((unsigned short)r0[k]) * e0 + bf2f((unsigned short)r1[k]) * e1)
                                + (bf2f((unsigned short)r2[k]) * e2 + bf2f((unsigned short)r3[k]) * e3);
                    a0 = f0; a1 = f1; a2 = f2; a3 = f3;
                    r0 = q0; r1 = q1; r2 = q2; r3 = q3;
                }
                {
                    float e0 = __expf(lrelu(a0 + adh));
                    float e1 = __expf(lrelu(a1 + adh));
                    float e2 = __expf(lrelu(a2 + adh));
                    float e3 = __expf(lrelu(a3 + adh));
                    esum += (e0 + e1) + (e2 + e3);
                    #pragma unroll
                    for (int k = 0; k < 8; k++)
                        acc[k] += (bf2f((unsigned short)r0[k]) * e0 + bf2f((unsigned short)r1[k]) * e1)
                                + (bf2f((unsigned short)r2[k]) * e2 + bf2f((unsigned short)r3[k]) * e3);
                    j += 8;
                }
            }
            if (j + 4 <= deg) {
                int p = beg + j + half * 2;
                int s0 = csr[p], s1 = csr[p + 1];
                float a0 = *(const float*)(ab + ((unsigned)(s0 << 4) + ho));
                float a1 = *(const float*)(ab + ((unsigned)(s1 << 4) + ho));
                short8 r0 = *(const short8*)(xb + ((unsigned)(s0 << 9) + co));
                short8 r1 = *(const short8*)(xb + ((unsigned)(s1 << 9) + co));
                float e0 = __expf(lrelu(a0 + adh));
                float e1 = __expf(lrelu(a1 + adh));
                esum += e0 + e1;
                #pragma unroll
                for (int k = 0; k < 8; k++)
                    acc[k] += bf2f((unsigned short)r0[k]) * e0 + bf2f((unsigned short)r1[k]) * e1;
                j += 4;
            }
            for (; j < deg; j += 2) {
                int jj = j + half;
                if (jj < deg) {
                    int s = csr[beg + jj];
                    float a0 = *(const float*)(ab + ((unsigned)(s << 4) + ho));
                    short8 r = *(const short8*)(xb + ((unsigned)(s << 9) + co));
                    float e = __expf(lrelu(a0 + adh));
                    esum += e;
                    #pragma unroll
                    for (int k = 0; k < 8; k++) acc[k] += bf2f((unsigned short)r[k]) * e;
                }
            }
        }
        #pragma unroll
        for (int k = 0; k < 8; k++) acc[k] += __shfl_xor(acc[k], 32);
        esum += __shfl_xor(esum, 32);
        if (half == 0) {
            short8 o;
            if (n < NN) {
                float rs = 1.f / (esum + 1e-16f);
                float4 bl = *(const float4*)(b1 + c * 8);
                float4 bh = *(const float4*)(b1 + c * 8 + 4);
                float bb[8] = {bl.x, bl.y, bl.z, bl.w, bh.x, bh.y, bh.z, bh.w};
                #pragma unroll
                for (int k = 0; k < 8; k++)
                    o[k] = (short)f2bf(fmaxf(acc[k] * rs + bb[k], 0.f));
            } else {
                #pragma unroll
                for (int k = 0; k < 8; k++) o[k] = 0;
            }
            *(short8*)(Ash + (((unsigned)(m * 32 + (c ^ (m & 7)))) << 4)) = o;
        }
    }

    // ---- phase 2: B fragments from pre-converted bf16 W2 (L2-hot) ----
    int colL = lane & 15, quad = lane >> 4;
    short8 bf[8];
    {
        const unsigned short* wp = w2b + (w * 16 + colL) * 256;
        #pragma unroll
        for (int kc = 0; kc < 8; kc++)
            bf[kc] = *(const short8*)(wp + (kc * 4 + quad) * 8);
    }
    __syncthreads();   // all Ash rows written

    // ---- phase 3: 32x64 MFMA over K=256 ----
    f32x4 acc2[2];
    #pragma unroll
    for (int mi = 0; mi < 2; mi++) acc2[mi] = (f32x4){0.f, 0.f, 0.f, 0.f};
    #pragma unroll
    for (int kc = 0; kc < 8; kc++) {
        int uA = kc * 4 + quad;
        #pragma unroll
        for (int mi = 0; mi < 2; mi++) {
            int mm = mi * 16 + colL;
            short8 af = *(const short8*)(Ash + (((unsigned)(mm * 32 + (uA ^ (mm & 7)))) << 4));
            acc2[mi] = __builtin_amdgcn_mfma_f32_16x16x32_bf16(af, bf[kc], acc2[mi], 0, 0, 0);
        }
    }

    // ---- phase 4: attention partial sums (NH=1) ----
    {
        float asv = atts2[w * 16 + colL];
        float adv = attd2[w * 16 + colL];
        #pragma unroll
        for (int mi = 0; mi < 2; mi++) {
            float ps[4], pd[4];
            #pragma unroll
            for (int r = 0; r < 4; r++) { ps[r] = acc2[mi][r] * asv; pd[r] = acc2[mi][r] * adv; }
            #pragma unroll
            for (int off = 1; off < 16; off <<= 1)
                #pragma unroll
                for (int r = 0; r < 4; r++) {
                    ps[r] += __shfl_xor(ps[r], off);
                    pd[r] += __shfl_xor(pd[r], off);
                }
            if (colL == 0) {
                #pragma unroll
                for (int r = 0; r < 4; r++) {
                    int rloc = mi * 16 + quad * 4 + r;
                    scsh[(w * NB + rloc) * 2 + 0] = ps[r];
                    scsh[(w * NB + rloc) * 2 + 1] = pd[r];
                }
            }
        }
    }
    __syncthreads();   // Ash reads done (overlay safe), scsh complete

    // ---- phase 5: C repack (bf16) + score reduce + coalesced store ----
    #pragma unroll
    for (int mi = 0; mi < 2; mi++)
        #pragma unroll
        for (int r = 0; r < 4; r++)
            Csh[(size_t)(mi * 16 + quad * 4 + r) * 72 + w * 16 + colL] = f2bf(acc2[mi][r]);
    if (t < NB) {
        int row = m0 + t;
        if (row < NN) {
            float s = 0.f, d = 0.f;
            #pragma unroll
            for (int ww = 0; ww < 4; ww++) {
                s += scsh[(ww * NB + t) * 2 + 0];
                d += scsh[(ww * NB + t) * 2 + 1];
            }
            as2[row] = s;
            ad2[row] = d;
        }
    }
    __syncthreads();
    {
        int mm = t >> 3, u = t & 7;   // 256 threads = 32 rows x 8 units
        int row = m0 + mm;
        if (row < NN)
            *(short8*)(xt2 + (size_t)row * 64 + u * 8) =
                *(const short8*)(Csh + (size_t)mm * 72 + u * 8);
    }
}

// ---------------- Layer-2 aggregation + fc + sigmoid: pipelined quarter-wave/edge ----------------
__global__ __launch_bounds__(256) void k_l2_agg(
    const unsigned short* __restrict__ xt2, const float* __restrict__ as2,
    const float* __restrict__ ad2, const int* __restrict__ rowptr,
    const int* __restrict__ csr, const float* __restrict__ b2,
    const float* __restrict__ fcw, const float* __restrict__ fcb,
    float* __restrict__ out)
{
    int t = threadIdx.x;
    int lane = t & 63, w = t >> 6;
    int n = blockIdx.x * 4 + w;
    int beg = rowptr[n], deg = rowptr[n + 1] - beg;
    int q = lane >> 4, c = lane & 15;   // lane owns channels 4c..4c+3 (8B loads)
    float adv = ad2[n];
    const char* xb = (const char*)xt2;
    unsigned co = (unsigned)(c << 3);

    float acc[4] = {0.f, 0.f, 0.f, 0.f};
    float esum = 0.f;
    int j = 0;
    if (deg >= 8) {
        int p = beg + q * 2;
        int s0 = csr[p], s1 = csr[p + 1];
        float a0 = as2[s0], a1 = as2[s1];
        uint2 r0 = *(const uint2*)(xb + ((unsigned)(s0 << 7) + co));
        uint2 r1 = *(const uint2*)(xb + ((unsigned)(s1 << 7) + co));
        for (; j + 16 <= deg; j += 8) {
            int p2 = beg + j + 8 + q * 2;
            int u0 = csr[p2], u1 = csr[p2 + 1];
            float f0 = as2[u0], f1 = as2[u1];
            uint2 q0 = *(const uint2*)(xb + ((unsigned)(u0 << 7) + co));
            uint2 q1 = *(const uint2*)(xb + ((unsigned)(u1 << 7) + co));
            float e0 = __expf(lrelu(a0 + adv));
            float e1 = __expf(lrelu(a1 + adv));
            esum += e0 + e1;
            acc[0] += bf2f((unsigned short)(r0.x & 0xffff)) * e0 + bf2f((unsigned short)(r1.x & 0xffff)) * e1;
            acc[1] += bf2f((unsigned short)(r0.x >> 16)) * e0 + bf2f((unsigned short)(r1.x >> 16)) * e1;
            acc[2] += bf2f((unsigned short)(r0.y & 0xffff)) * e0 + bf2f((unsigned short)(r1.y & 0xffff)) * e1;
            acc[3] += bf2f((unsigned short)(r0.y >> 16)) * e0 + bf2f((unsigned short)(r1.y >> 16)) * e1;
            a0 = f0; a1 = f1; r0 = q0; r1 = q1;
        }
        {
            float e0 = __expf(lrelu(a0 + adv));
            float e1 = __expf(lrelu(a1 + adv));
            esum += e0 + e1;
            acc[0] += bf2f((unsigned short)(r0.x & 0xffff)) * e0 + bf2f((unsigned short)(r1.x & 0xffff)) * e1;
            acc[1] += bf2f((unsigned short)(r0.x >> 16)) * e0 + bf2f((unsigned short)(r1.x >> 16)) * e1;
            acc[2] += bf2f((unsigned short)(r0.y & 0xffff)) * e0 + bf2f((unsigned short)(r1.y & 0xffff)) * e1;
            acc[3] += bf2f((unsigned short)(r0.y >> 16)) * e0 + bf2f((unsigned short)(r1.y >> 16)) * e1;
            j += 8;
        }
    }
    for (; j < deg; j += 4) {
        int jj = j + q;
        if (jj < deg) {
            int s = csr[beg + jj];
            float a0 = as2[s];
            uint2 r = *(const uint2*)(xb + ((unsigned)(s << 7) + co));
            float e = __expf(lrelu(a0 + adv));
            esum += e;
            acc[0] += bf2f((unsigned short)(r.x & 0xffff)) * e;
            acc[1] += bf2f((unsigned short)(r.x >> 16)) * e;
            acc[2] += bf2f((unsigned short)(r.y & 0xffff)) * e;
            acc[3] += bf2f((unsigned short)(r.y >> 16)) * e;
        }
    }
    #pragma unroll
    for (int k = 0; k < 4; k++) {
        acc[k] += __shfl_xor(acc[k], 16);
        acc[k] += __shfl_xor(acc[k], 32);
    }
    esum += __shfl_xor(esum, 16);
    esum += __shfl_xor(esum, 32);
    float rs = 1.f / (esum + 1e-16f);
    float4 bv = *(const float4*)(b2 + c * 4);
    float4 fv = *(const float4*)(fcw + c * 4);
    float z = fmaxf(acc[0] * rs + bv.x, 0.f) * fv.x
            + fmaxf(acc[1] * rs + bv.y, 0.f) * fv.y
            + fmaxf(acc[2] * rs + bv.z, 0.f) * fv.z
            + fmaxf(acc[3] * rs + bv.w, 0.f) * fv.w;
    #pragma unroll
    for (int off = 8; off; off >>= 1) z += __shfl_xor(z, off);
    if (lane == 0) out[n] = 1.f / (1.f + __expf(-(z + fcb[0])));
}

// ---------------- launch ----------------

extern "C" void kernel_launch(void* const* d_in, const int* in_sizes, int n_in,
                              void* d_out, int out_size, void* d_ws, size_t ws_size,
                              hipStream_t stream) {
    const float* x    = (const float*)d_in[0];
    const int*   ei   = (const int*)d_in[1];
    const float* W1   = (const float*)d_in[2];
    const float* as1w = (const float*)d_in[3];
    const float* ad1w = (const float*)d_in[4];
    const float* b1   = (const float*)d_in[5];
    const float* W2   = (const float*)d_in[6];
    const float* as2w = (const float*)d_in[7];
    const float* ad2w = (const float*)d_in[8];
    const float* b2   = (const float*)d_in[9];
    const float* fcw  = (const float*)d_in[10];
    const float* fcb  = (const float*)d_in[11];
    float* out = (float*)d_out;

    const int* src = ei;
    const int* dst = ei + EE;

    char* base = (char*)d_ws;
    size_t off = 0;
    auto alloc = [&](size_t bytes) -> void* {
        void* p = base + off;
        off = (off + bytes + 255) & ~(size_t)255;
        return p;
    };
    int*   rowptr   = (int*)alloc((NN + 1) * sizeof(int));
    int*   cnt      = (int*)alloc(NN * sizeof(int));
    int*   tmp      = (int*)alloc(NN * sizeof(int));
    int*   bsum     = (int*)alloc(SG * sizeof(int));
    int*   boff     = (int*)alloc(SG * sizeof(int));
    int*   writeptr = (int*)alloc(NN * sizeof(int));
    int*   csr      = (int*)alloc(ET * sizeof(int));
    unsigned short* xt1 = (unsigned short*)alloc((size_t)NN * 256 * sizeof(unsigned short));
    unsigned short* xt2 = (unsigned short*)alloc((size_t)NN * 64 * sizeof(unsigned short));
    unsigned short* w2b = (unsigned short*)alloc(64 * 256 * sizeof(unsigned short));
    float* as1      = (float*)alloc(NN * 4 * sizeof(float));
    float* ad1      = (float*)alloc(NN * 4 * sizeof(float));
    float* as2      = (float*)alloc(NN * sizeof(float));
    float* ad2      = (float*)alloc(NN * sizeof(float));

    // CSR build (+ W2 bf16 conversion piggybacked on first 16 hist blocks)
    hipMemsetAsync(cnt, 0, NN * sizeof(int), stream);
    k_hist<<<(EE + 255) / 256, 256, 0, stream>>>(dst, cnt, W2, w2b);
    k_scan1<<<SG, 256, 0, stream>>>(cnt, tmp, bsum);
    k_scan2<<<1, 256, 0, stream>>>(bsum, boff);
    k_scan3_prep<<<SG, 256, 0, stream>>>(tmp, boff, rowptr, writeptr, csr);

    // GEMM1 (MFMA) striped with scatter in one heterogeneous launch
    int fused_blocks = GB1 + (EE + 255) / 256;   // 782 + 3125 = 3907
    k_gemm1_scatter<<<fused_blocks, 256, 0, stream>>>(
        x, W1, as1w, ad1w, xt1, as1, ad1, NN, src, dst, writeptr, csr);

    // fused layer-1 aggregation + GEMM2 (h1 never touches global), 32 nodes/block
    k_l1_gemm2<<<GB2, 256, 0, stream>>>(
        xt1, as1, ad1, rowptr, csr, b1, w2b, as2w, ad2w, xt2, as2, ad2);

    k_l2_agg<<<(NN + 3) / 4, 256, 0, stream>>>(xt2, as2, ad2, rowptr, csr, b2, fcw, fcb, out);
}